// Round 11
// baseline (176.760 us; speedup 1.0000x reference)
//
#include <hip/hip_runtime.h>
#include <math.h>

// Problem constants (fixed by the reference setup_inputs)
#define NIMG   64
#define CDIM   64
#define HWPX   4096
#define KCL    128
#define TL     64                // pixels per chunk
#define SHIFT  10.0f             // softmax shift folded into bias
#define RSQRT128 0.08838834764831845f

// LDS strides in shorts (multiples of 8 so b128 stays 16B-aligned)
#define XP_S 72    // xp planes [64 p][64 c]
#define XC_S 72    // xc plane  [64 c][64 slot]
#define PH_S 72    // ph plane  [128 k][64 slot]

typedef __attribute__((ext_vector_type(8))) short short8; // 8 bf16
typedef __attribute__((ext_vector_type(4))) float f32x4;  // MFMA C/D

#define MFMA(a, b, c) __builtin_amdgcn_mfma_f32_16x16x32_bf16((a), (b), (c), 0, 0, 0)

// Pack the truncated-bf16 prefixes of two floats into one u32 with a single
// v_perm_b32: bytes {f0.b2, f0.b3, f1.b2, f1.b3}.
#define PERM_HI16 0x07060302u

// Relaxed workgroup barrier: LDS-visibility only (no vmcnt(0) drain).
#define BAR() do {                                          \
    asm volatile("s_waitcnt lgkmcnt(0)" ::: "memory");      \
    __builtin_amdgcn_s_barrier();                           \
    __builtin_amdgcn_sched_barrier(0);                      \
} while (0)

// ---------------------------------------------------------------------------
// HISTORY (measured):
// R11 FAIL launch_bounds(256,4)->spill; R12/R13 NEUTRAL (blocks/VALU);
// R14 REGRESS (remap conflicts); R15 WIN -1.8us (dbuf, 3->2 bar/chunk);
// R16 NULL (small DS ops); R17 WIN -1.8us (TL=64, 16 bars) = 41.8us;
// R18 REGRESS (2x2 wave partition: conflicts 3.1M); R19 no-data;
// R20 NEUTRAL (softmax-tail pipeline, 42.2us) -- kept (equal, within noise).
// => Main kernel is on a latency plateau: no pipe >40%, all throughput
//    levers null. BUT e2e - main ~= 81us CONSTANT across all rounds:
//    finalize kernel + 2nd graph-node launch dwarf remaining main levers.
// R21: FUSE finalize into the main kernel (last-block-per-image):
//    write partials -> __syncthreads (drain) -> t0: __threadfence (device
//    release; L2 wb across XCDs) + atomicAdd(counter[n]) -> 8th block
//    re-fences (acquire/inv) and finalizes image n (bit-identical order
//    to the old finalize kernel). 64 finalizer tails overlap other blocks'
//    compute; the 2nd kernel launch disappears. Counters in d_ws (+1KB,
//    memset in-graph each iteration). Main loop body identical to R20.
// ---------------------------------------------------------------------------
template <int NP, int FUSED>
__global__ __launch_bounds__(256, 2)
void netvlad_main(const float* __restrict__ x,       // [N][C][HW]
                  const float* __restrict__ conv_w,  // [K][C]
                  const float* __restrict__ conv_b,  // [K]
                  const float* __restrict__ cent,    // [K][C]
                  float* __restrict__ vout,          // partials or atomic acc
                  float* __restrict__ asout,
                  int* __restrict__ counters,        // [N] (FUSED only)
                  float* __restrict__ outp)          // [N][K*C] (FUSED only)
{
    constexpr int PIXPART = HWPX / NP;   // pixels per block (512)
    constexpr int NCHUNK  = PIXPART / TL;  // 8

    __shared__ __align__(16) short xp_hi[2][TL * XP_S], xp_lo[2][TL * XP_S]; // 36.9 KB
    __shared__ __align__(16) short xc[2][CDIM * XC_S];                       // 18.4 KB
    __shared__ __align__(16) short ph[KCL * PH_S];                           // 18.4 KB
    __shared__ __align__(8) float2 redA2[2][4 * 32];  // ssq pairs [buf][wave][q]
    __shared__ __align__(8) float2 sumP2[2][4 * 32];  // exp-sum pairs [buf]

    const int t   = threadIdx.x;
    const int w   = t >> 6;             // wave 0..3
    const int l   = t & 63;
    const int l15 = l & 15, l4 = l >> 4;
    const int n    = blockIdx.x / NP;
    const int part = blockIdx.x - n * NP;
    const int q    = t & 31;            // staging pixel-pair id
    const int sg   = t >> 5;            // staging c-group (8 c's)
    const int p0   = (q & 15) + ((q & 16) << 1);   // 0..15, 32..47
    const int xslot = ((q >> 4) << 5) + 2 * (q & 15);  // kdim slot of p0

    // ---- W fragments in registers (once): A[m=k][kdim=c], 3-term split ----
    short8 wh[2][2], wl[2][2];
    #pragma unroll
    for (int kt = 0; kt < 2; ++kt) {
        const int krow = (2 * w + kt) * 16 + l15;
        #pragma unroll
        for (int ks = 0; ks < 2; ++ks) {
            const float4* wp = (const float4*)(conv_w + krow * CDIM + ks * 32 + l4 * 8);
            float4 wa = wp[0], wb = wp[1];
            float wv[8] = {wa.x, wa.y, wa.z, wa.w, wb.x, wb.y, wb.z, wb.w};
            #pragma unroll
            for (int j = 0; j < 8; ++j) {
                unsigned u = __builtin_bit_cast(unsigned, wv[j]);
                wh[kt][ks][j] = (short)(u >> 16);
                float hf = __builtin_bit_cast(float, u & 0xffff0000u);
                wl[kt][ks][j] = (short)(__builtin_bit_cast(unsigned, wv[j] - hf) >> 16);
            }
        }
    }
    // bias per D-row (k = (2w+kt)*16 + l4*4 + i), pre-shifted
    float cbr[2][4];
    #pragma unroll
    for (int kt = 0; kt < 2; ++kt)
        #pragma unroll
        for (int i = 0; i < 4; ++i)
            cbr[kt][i] = conv_b[(2 * w + kt) * 16 + l4 * 4 + i] - SHIFT;

    f32x4 acc2[2][4];                   // V tiles [kt][ct]
    #pragma unroll
    for (int a = 0; a < 2; ++a)
        #pragma unroll
        for (int b = 0; b < 4; ++b) acc2[a][b] = (f32x4)0.0f;
    float asr[2][4];                    // asum partials per D-row
    #pragma unroll
    for (int a = 0; a < 2; ++a)
        #pragma unroll
        for (int i = 0; i < 4; ++i) asr[a][i] = 0.f;

    const float* xbase = x + (size_t)n * CDIM * HWPX + part * PIXPART;

    float xv0[8], xv1[8];               // pixel p0 / p1 = p0+16

    // pipeline carry: chunk-j softmax numerators + 1/||x|| (consumed at j+1)
    float e[2][4][4];
    float rnv[4];

    #define LOADX(OFF) do {                                                 \
        _Pragma("unroll")                                                   \
        for (int j = 0; j < 8; ++j) {                                       \
            xv0[j] = xbase[(sg * 8 + j) * HWPX + (OFF) + p0];               \
            xv1[j] = xbase[(sg * 8 + j) * HWPX + (OFF) + p0 + 16];          \
        }                                                                   \
    } while (0)

    // stage: ssq pair + xp hi/lo rows (p0,p1) + xc plane into buffer `buf`.
    auto stage = [&](int buf) {
        float ssq0 = 0.f, ssq1 = 0.f;
        #pragma unroll
        for (int j = 0; j < 8; ++j) {
            ssq0 += xv0[j] * xv0[j];
            ssq1 += xv1[j] * xv1[j];
        }
        ssq0 += __shfl_xor(ssq0, 32);   // combine the wave's 2 sg's
        ssq1 += __shfl_xor(ssq1, 32);
        if (l < 32) redA2[buf][w * 32 + q] = make_float2(ssq0, ssq1);

        // xp row p0 (from xv0)
        {
            unsigned uh[4], ul[4];
            #pragma unroll
            for (int jp = 0; jp < 4; ++jp) {
                const unsigned u0 = __builtin_bit_cast(unsigned, xv0[2 * jp]);
                const unsigned u1 = __builtin_bit_cast(unsigned, xv0[2 * jp + 1]);
                uh[jp] = __builtin_amdgcn_perm(u1, u0, PERM_HI16);
                const float h0 = __builtin_bit_cast(float, u0 & 0xffff0000u);
                const float h1 = __builtin_bit_cast(float, u1 & 0xffff0000u);
                const unsigned lo0 = __builtin_bit_cast(unsigned, xv0[2 * jp] - h0);
                const unsigned lo1 = __builtin_bit_cast(unsigned, xv0[2 * jp + 1] - h1);
                ul[jp] = __builtin_amdgcn_perm(lo1, lo0, PERM_HI16);
            }
            *(uint4*)&xp_hi[buf][p0 * XP_S + sg * 8] = make_uint4(uh[0], uh[1], uh[2], uh[3]);
            *(uint4*)&xp_lo[buf][p0 * XP_S + sg * 8] = make_uint4(ul[0], ul[1], ul[2], ul[3]);
        }
        // xp row p1 (from xv1)
        {
            unsigned uh[4], ul[4];
            #pragma unroll
            for (int jp = 0; jp < 4; ++jp) {
                const unsigned u0 = __builtin_bit_cast(unsigned, xv1[2 * jp]);
                const unsigned u1 = __builtin_bit_cast(unsigned, xv1[2 * jp + 1]);
                uh[jp] = __builtin_amdgcn_perm(u1, u0, PERM_HI16);
                const float h0 = __builtin_bit_cast(float, u0 & 0xffff0000u);
                const float h1 = __builtin_bit_cast(float, u1 & 0xffff0000u);
                const unsigned lo0 = __builtin_bit_cast(unsigned, xv1[2 * jp] - h0);
                const unsigned lo1 = __builtin_bit_cast(unsigned, xv1[2 * jp + 1] - h1);
                ul[jp] = __builtin_amdgcn_perm(lo1, lo0, PERM_HI16);
            }
            *(uint4*)&xp_hi[buf][(p0 + 16) * XP_S + sg * 8] = make_uint4(uh[0], uh[1], uh[2], uh[3]);
            *(uint4*)&xp_lo[buf][(p0 + 16) * XP_S + sg * 8] = make_uint4(ul[0], ul[1], ul[2], ul[3]);
        }

        // xc plane (RNE bf16): pair (p0, p0+16) -> one b32 at (xslot, +1).
        #pragma unroll
        for (int j = 0; j < 8; ++j) {
            unsigned pk;
            asm("v_cvt_pk_bf16_f32 %0, %1, %2"
                : "=v"(pk) : "v"(xv0[j]), "v"(xv1[j]));
            *(unsigned*)&xc[buf][(sg * 8 + j) * XC_S + xslot] = pk;
        }
    };

    // mm1 + softmax numerators for chunk with buffer parity b; fills e, rnv,
    // and writes this chunk's sumP2[b] (visible after the following BAR).
    auto mm1_sec = [&](int b) {
        f32x4 a1[2][4];
        #pragma unroll
        for (int a = 0; a < 2; ++a)
            #pragma unroll
            for (int c = 0; c < 4; ++c) a1[a][c] = (f32x4)0.0f;
        #pragma unroll
        for (int ks = 0; ks < 2; ++ks) {
            #pragma unroll
            for (int pt = 0; pt < 4; ++pt) {
                short8 bh = *(short8*)&xp_hi[b][(pt * 16 + l15) * XP_S + ks * 32 + l4 * 8];
                short8 bl = *(short8*)&xp_lo[b][(pt * 16 + l15) * XP_S + ks * 32 + l4 * 8];
                #pragma unroll
                for (int kt = 0; kt < 2; ++kt) {
                    a1[kt][pt] = MFMA(wh[kt][ks], bh, a1[kt][pt]);
                    a1[kt][pt] = MFMA(wh[kt][ks], bl, a1[kt][pt]);
                    a1[kt][pt] = MFMA(wl[kt][ks], bh, a1[kt][pt]);
                }
            }
        }

        // per-column 1/||x||
        float2 ra0 = redA2[b][l15],           ra1 = redA2[b][32 + l15];
        float2 ra2 = redA2[b][64 + l15],      ra3 = redA2[b][96 + l15];
        float2 rb0 = redA2[b][16 + l15],      rb1 = redA2[b][48 + l15];
        float2 rb2 = redA2[b][80 + l15],      rb3 = redA2[b][112 + l15];
        rnv[0] = 1.0f / fmaxf(sqrtf((ra0.x + ra1.x) + (ra2.x + ra3.x)), 1e-12f);
        rnv[1] = 1.0f / fmaxf(sqrtf((ra0.y + ra1.y) + (ra2.y + ra3.y)), 1e-12f);
        rnv[2] = 1.0f / fmaxf(sqrtf((rb0.x + rb1.x) + (rb2.x + rb3.x)), 1e-12f);
        rnv[3] = 1.0f / fmaxf(sqrtf((rb0.y + rb1.y) + (rb2.y + rb3.y)), 1e-12f);

        // in-register softmax numerators (no max pass; bias pre-shifted)
        float sp[4] = {0.f, 0.f, 0.f, 0.f};
        #pragma unroll
        for (int kt = 0; kt < 2; ++kt)
            #pragma unroll
            for (int pt = 0; pt < 4; ++pt)
                #pragma unroll
                for (int i = 0; i < 4; ++i) {
                    float ev = __expf(fmaf(a1[kt][pt][i], rnv[pt], cbr[kt][i]));
                    e[kt][pt][i] = ev;
                    sp[pt] += ev;
                }
        #pragma unroll
        for (int pt = 0; pt < 4; ++pt) {
            sp[pt] += __shfl_xor(sp[pt], 16);
            sp[pt] += __shfl_xor(sp[pt], 32);   // wave-sum over its 32 k's
        }
        if (l4 == 0)      sumP2[b][w * 32 + l15]      = make_float2(sp[0], sp[1]);
        else if (l4 == 1) sumP2[b][w * 32 + 16 + l15] = make_float2(sp[2], sp[3]);
    };

    // ph + mm2 for the chunk with buffer parity pb (its sumP2/xc), consuming
    // the carried e/rnv. Runs one iteration after mm1_sec(pb).
    auto ph_mm2 = [&](int pb) {
        float2 q0 = sumP2[pb][l15],       q1 = sumP2[pb][32 + l15];
        float2 q2 = sumP2[pb][64 + l15],  q3 = sumP2[pb][96 + l15];
        float2 r0 = sumP2[pb][16 + l15],  r1 = sumP2[pb][48 + l15];
        float2 r2 = sumP2[pb][80 + l15],  r3 = sumP2[pb][112 + l15];
        float rden[4], rdn2[4];
        rden[0] = 1.0f / ((q0.x + q1.x) + (q2.x + q3.x));
        rden[1] = 1.0f / ((q0.y + q1.y) + (q2.y + q3.y));
        rden[2] = 1.0f / ((r0.x + r1.x) + (r2.x + r3.x));
        rden[3] = 1.0f / ((r0.y + r1.y) + (r2.y + r3.y));
        #pragma unroll
        for (int pt = 0; pt < 4; ++pt) rdn2[pt] = rden[pt] * rnv[pt];

        // P' -> ph: two b32 per (kt,i): slots (2l15,2l15+1), (+32)
        #pragma unroll
        for (int kt = 0; kt < 2; ++kt)
            #pragma unroll
            for (int i = 0; i < 4; ++i) {
                const int row = (2 * w + kt) * 16 + l4 * 4 + i;
                const float e0 = e[kt][0][i], e1 = e[kt][1][i];
                const float e2 = e[kt][2][i], e3 = e[kt][3][i];
                asr[kt][i] = fmaf(e0, rden[0], asr[kt][i]);
                asr[kt][i] = fmaf(e1, rden[1], asr[kt][i]);
                asr[kt][i] = fmaf(e2, rden[2], asr[kt][i]);
                asr[kt][i] = fmaf(e3, rden[3], asr[kt][i]);
                const float p0f = e0 * rdn2[0], p1f = e1 * rdn2[1];
                const float p2f = e2 * rdn2[2], p3f = e3 * rdn2[3];
                unsigned pk01, pk23;
                asm("v_cvt_pk_bf16_f32 %0, %1, %2" : "=v"(pk01) : "v"(p0f), "v"(p1f));
                asm("v_cvt_pk_bf16_f32 %0, %1, %2" : "=v"(pk23) : "v"(p2f), "v"(p3f));
                *(unsigned*)&ph[row * PH_S + 2 * l15]      = pk01;
                *(unsigned*)&ph[row * PH_S + 32 + 2 * l15] = pk23;
            }
        // no barrier: mm2 reads only the ph rows this wave just wrote.

        // mm2: V[k][c] += P' @ Xc^T (kdim = 64 interleaved slots)
        short8 xh2[4][2];
        #pragma unroll
        for (int ct = 0; ct < 4; ++ct)
            #pragma unroll
            for (int hh = 0; hh < 2; ++hh)
                xh2[ct][hh] = *(short8*)&xc[pb][(ct * 16 + l15) * XC_S + hh * 32 + l4 * 8];
        #pragma unroll
        for (int kt = 0; kt < 2; ++kt) {
            short8 ah0 = *(short8*)&ph[((2 * w + kt) * 16 + l15) * PH_S + l4 * 8];
            short8 ah1 = *(short8*)&ph[((2 * w + kt) * 16 + l15) * PH_S + 32 + l4 * 8];
            #pragma unroll
            for (int ct = 0; ct < 4; ++ct) {
                acc2[kt][ct] = MFMA(ah0, xh2[ct][0], acc2[kt][ct]);
                acc2[kt][ct] = MFMA(ah1, xh2[ct][1], acc2[kt][ct]);
            }
        }
    };

    // ---- prologue --------------------------------------------------------
    LOADX(0);
    stage(0);
    if (NCHUNK > 1) LOADX(TL);
    BAR();                               // stage(0) visible
    if (NCHUNK > 1) stage(1);
    if (NCHUNK > 2) LOADX(2 * TL);
    mm1_sec(0);
    BAR();                               // sumP2[0] + stage(1) visible

    // ---- main pipeline ---------------------------------------------------
    for (int ch = 1; ch < NCHUNK; ++ch) {
        ph_mm2((ch - 1) & 1);            // finish chunk ch-1
        BAR();                           // BAR_a: xc[(ch-1)&1] reads done
        if (ch + 1 < NCHUNK) stage((ch + 1) & 1);
        if (ch + 2 < NCHUNK) LOADX((ch + 2) * TL);
        mm1_sec(ch & 1);                 // chunk ch numerators
        BAR();                           // BAR_b: sumP2[ch&1] + stage visible
    }
    ph_mm2((NCHUNK - 1) & 1);            // epilogue: finish last chunk
    #undef LOADX

    // ---- V write (coalesced: lanes l15 -> consecutive c) ------------------
    float* vg = FUSED ? vout + (size_t)blockIdx.x * KCL * CDIM
                      : vout + (size_t)n * KCL * CDIM;
    #pragma unroll
    for (int kt = 0; kt < 2; ++kt)
        #pragma unroll
        for (int ct = 0; ct < 4; ++ct)
            #pragma unroll
            for (int i = 0; i < 4; ++i) {
                const int row = (2 * w + kt) * 16 + l4 * 4 + i;
                const int col = ct * 16 + l15;
                if (FUSED) vg[row * CDIM + col] = acc2[kt][ct][i];
                else       atomicAdd(&vg[row * CDIM + col], acc2[kt][ct][i]);
            }

    // ---- asum: reduce over l15 lanes, lane0-of-16 writes ------------------
    #pragma unroll
    for (int kt = 0; kt < 2; ++kt)
        #pragma unroll
        for (int i = 0; i < 4; ++i) {
            float v = asr[kt][i];
            v += __shfl_xor(v, 1); v += __shfl_xor(v, 2);
            v += __shfl_xor(v, 4); v += __shfl_xor(v, 8);
            if (l15 == 0) {
                const int row = (2 * w + kt) * 16 + l4 * 4 + i;
                if (FUSED) asout[blockIdx.x * KCL + row] = v;
                else       atomicAdd(&asout[n * KCL + row], v);
            }
        }

    if (!FUSED) return;

    // ---- fused finalize: last block of image n reduces + normalizes -------
    __syncthreads();                 // all partial stores drained (vmcnt0+bar)
    __shared__ int lastFlag;
    if (t == 0) {
        __threadfence();             // device-scope release (L2 writeback)
        lastFlag = (atomicAdd(&counters[n], 1) == NP - 1) ? 1 : 0;
    }
    __syncthreads();
    if (!lastFlag) return;
    __threadfence();                 // device-scope acquire (invalidate)

    const int kk = t >> 4;           // 0..15
    const int c0 = (t & 15) * 4;
    #pragma unroll
    for (int kg = 0; kg < 8; ++kg) {
        const int k = kg * 16 + kk;
        float vs[4] = {0.f, 0.f, 0.f, 0.f};
        float av = 0.f;
        #pragma unroll
        for (int pt = 0; pt < NP; ++pt) {
            const float* vg2 = vout + (((size_t)n * NP + pt) * KCL + k) * CDIM + c0;
            float4 a = *(const float4*)vg2;
            vs[0] += a.x; vs[1] += a.y; vs[2] += a.z; vs[3] += a.w;
            av += asout[(n * NP + pt) * KCL + k];
        }
        float4 cq = *(const float4*)(cent + k * CDIM + c0);
        float cc[4] = {cq.x, cq.y, cq.z, cq.w};
        float ss = 0.f;
        #pragma unroll
        for (int j = 0; j < 4; ++j) {
            vs[j] -= av * cc[j];
            ss += vs[j] * vs[j];
        }
        ss += __shfl_xor(ss, 1); ss += __shfl_xor(ss, 2);
        ss += __shfl_xor(ss, 4); ss += __shfl_xor(ss, 8);
        const float s = (1.0f / fmaxf(sqrtf(ss), 1e-12f)) * RSQRT128;
        float4 o;
        o.x = vs[0] * s; o.y = vs[1] * s; o.z = vs[2] * s; o.w = vs[3] * s;
        *(float4*)(outp + (size_t)n * KCL * CDIM + k * CDIM + c0) = o;
    }
}

// ---------------------------------------------------------------------------
// Kernel 2 (FALLBACK tier only): sum atomic accumulators; normalize.
// ---------------------------------------------------------------------------
template <int NPARTS>
__global__ __launch_bounds__(256)
void netvlad_finalize(const float* __restrict__ vpart,   // [N][NPARTS][K][C]
                      const float* __restrict__ aspart,  // [N][NPARTS][K]
                      const float* __restrict__ cent,    // [K][C]
                      float* __restrict__ out)           // [N][K*C]
{
    const int t = threadIdx.x;
    const int n  = blockIdx.x >> 3;
    const int kg = blockIdx.x & 7;
    const int k  = kg * 16 + (t >> 4);
    const int c0 = (t & 15) * 4;

    float vsum[4] = {0.f, 0.f, 0.f, 0.f};
    float av = 0.f;
    #pragma unroll
    for (int pt = 0; pt < NPARTS; ++pt) {
        const float* vg = vpart + (((size_t)n * NPARTS + pt) * KCL + k) * CDIM + c0;
        float4 a = *(const float4*)vg;
        vsum[0] += a.x; vsum[1] += a.y; vsum[2] += a.z; vsum[3] += a.w;
        av += aspart[(n * NPARTS + pt) * KCL + k];
    }

    float4 cq = *(const float4*)(cent + k * CDIM + c0);
    float cc[4] = {cq.x, cq.y, cq.z, cq.w};
    float ss = 0.f;
    #pragma unroll
    for (int j = 0; j < 4; ++j) {
        vsum[j] -= av * cc[j];
        ss += vsum[j] * vsum[j];
    }
    ss += __shfl_xor(ss, 1); ss += __shfl_xor(ss, 2);
    ss += __shfl_xor(ss, 4); ss += __shfl_xor(ss, 8);
    const float s = (1.0f / fmaxf(sqrtf(ss), 1e-12f)) * RSQRT128;

    float4 o;
    o.x = vsum[0] * s; o.y = vsum[1] * s; o.z = vsum[2] * s; o.w = vsum[3] * s;
    *(float4*)(out + (size_t)n * KCL * CDIM + k * CDIM + c0) = o;
}

// ---------------------------------------------------------------------------
extern "C" void kernel_launch(void* const* d_in, const int* in_sizes, int n_in,
                              void* d_out, int out_size, void* d_ws, size_t ws_size,
                              hipStream_t stream) {
    const float* x     = (const float*)d_in[0];   // [64,64,64,64]
    const float* cent  = (const float*)d_in[1];   // [128,64]
    const float* convw = (const float*)d_in[2];   // [128,64]
    const float* convb = (const float*)d_in[3];   // [128]
    float* out = (float*)d_out;

    // Fused layout: [0,1KB) counters (64 ints), then vpart, then aspart.
    const size_t part_floats = (size_t)NIMG * 8 * (KCL * CDIM + KCL);
    const size_t need_fused  = 1024 + part_floats * sizeof(float);

    if (ws_size >= need_fused) {
        int*   counters = (int*)d_ws;
        float* vws  = (float*)((char*)d_ws + 1024);               // [N][8][K][C]
        float* asws = vws + (size_t)NIMG * 8 * KCL * CDIM;        // [N][8][K]
        hipMemsetAsync(d_ws, 0, 1024, stream);                    // zero counters
        netvlad_main<8, 1><<<dim3(NIMG * 8), dim3(256), 0, stream>>>(
            x, convw, convb, cent, vws, asws, counters, out);
    } else {
        // atomic fallback (ws too small for partials + counters)
        float* vws  = (float*)d_ws;                               // [N][K][C]
        float* asws = vws + (size_t)NIMG * KCL * CDIM;            // [N][K]
        const size_t zb = (size_t)NIMG * (KCL * CDIM + KCL) * sizeof(float);
        hipMemsetAsync(d_ws, 0, zb, stream);
        netvlad_main<8, 0><<<dim3(NIMG * 8), dim3(256), 0, stream>>>(
            x, convw, convb, cent, vws, asws, nullptr, out);
        netvlad_finalize<1><<<dim3(NIMG * 8), dim3(256), 0, stream>>>(
            vws, asws, cent, out);
    }
}

// Round 12
// 152.294 us; speedup vs baseline: 1.1606x; 1.1606x over previous
//
#include <hip/hip_runtime.h>
#include <math.h>

// Problem constants (fixed by the reference setup_inputs)
#define NIMG   64
#define CDIM   64
#define HWPX   4096
#define KCL    128
#define TL     64                // pixels per chunk
#define SHIFT  10.0f             // softmax shift folded into bias
#define RSQRT128 0.08838834764831845f

// LDS strides in shorts (multiples of 8 so b128 stays 16B-aligned)
#define XP_S 72    // xp planes [64 p][64 c]
#define XC_S 72    // xc plane  [64 c][64 slot]
#define PH_S 72    // ph plane  [128 k][64 slot]

typedef __attribute__((ext_vector_type(8))) short short8; // 8 bf16
typedef __attribute__((ext_vector_type(4))) float f32x4;  // MFMA C/D

#define MFMA(a, b, c) __builtin_amdgcn_mfma_f32_16x16x32_bf16((a), (b), (c), 0, 0, 0)

// Pack the truncated-bf16 prefixes of two floats into one u32 with a single
// v_perm_b32: bytes {f0.b2, f0.b3, f1.b2, f1.b3}.
#define PERM_HI16 0x07060302u

// Relaxed workgroup barrier: LDS-visibility only (no vmcnt(0) drain).
#define BAR() do {                                          \
    asm volatile("s_waitcnt lgkmcnt(0)" ::: "memory");      \
    __builtin_amdgcn_s_barrier();                           \
    __builtin_amdgcn_sched_barrier(0);                      \
} while (0)

// ---------------------------------------------------------------------------
// HISTORY (measured):
// R11 FAIL lb(256,4)->spill; R12/R13 NEUTRAL; R14 REGRESS (remap);
// R15 WIN -1.8us (dbuf 3->2 bar); R16 NULL; R17 WIN -1.8us (TL=64) = 41.8;
// R18 REGRESS (wave partition); R20 NEUTRAL (pipeline, kept) = 42.2 main.
// R21 REGRESS (fused finalize w/ partial-STORES + per-block threadfence):
//   main 42->120us. Mechanism: dirty-L2 writeback per release fence x512 +
//   acquire invalidations killing x locality. DIAGNOSTIC WIN: without the
//   2nd kernel, e2e-main gap = 56us (vs 81) => finalize+launch ~= 25us
//   addressable; ~56us harness-fixed.
// R22: fuse with CLEAN-L2 design: V/asum accumulated via device-scope
//   atomicAdd (m20: device-coherent by default; proven in the original
//   fallback path) into one [N][K][C] accumulator -> L2 has no dirty
//   partials -> release is ~free. Counter via __hip_atomic_fetch_add
//   (ACQ_REL, AGENT); last block per image does one __threadfence
//   (acquire/inv) then plain float4 reads + normalize + out write.
//   No XCD-mapping assumptions (G16-clean message passing).
//   Main loop body identical to R20.
// ---------------------------------------------------------------------------
template <int NP, int FUSED>
__global__ __launch_bounds__(256, 2)
void netvlad_main(const float* __restrict__ x,       // [N][C][HW]
                  const float* __restrict__ conv_w,  // [K][C]
                  const float* __restrict__ conv_b,  // [K]
                  const float* __restrict__ cent,    // [K][C]
                  float* __restrict__ vacc,          // [N][K][C] atomic acc
                  float* __restrict__ asacc,         // [N][K]    atomic acc
                  int* __restrict__ counters,        // [N] (FUSED only)
                  float* __restrict__ outp)          // [N][K*C] (FUSED only)
{
    constexpr int PIXPART = HWPX / NP;   // pixels per block (512)
    constexpr int NCHUNK  = PIXPART / TL;  // 8

    __shared__ __align__(16) short xp_hi[2][TL * XP_S], xp_lo[2][TL * XP_S]; // 36.9 KB
    __shared__ __align__(16) short xc[2][CDIM * XC_S];                       // 18.4 KB
    __shared__ __align__(16) short ph[KCL * PH_S];                           // 18.4 KB
    __shared__ __align__(8) float2 redA2[2][4 * 32];  // ssq pairs [buf][wave][q]
    __shared__ __align__(8) float2 sumP2[2][4 * 32];  // exp-sum pairs [buf]

    const int t   = threadIdx.x;
    const int w   = t >> 6;             // wave 0..3
    const int l   = t & 63;
    const int l15 = l & 15, l4 = l >> 4;
    const int n    = blockIdx.x / NP;
    const int part = blockIdx.x - n * NP;
    const int q    = t & 31;            // staging pixel-pair id
    const int sg   = t >> 5;            // staging c-group (8 c's)
    const int p0   = (q & 15) + ((q & 16) << 1);   // 0..15, 32..47
    const int xslot = ((q >> 4) << 5) + 2 * (q & 15);  // kdim slot of p0

    // ---- W fragments in registers (once): A[m=k][kdim=c], 3-term split ----
    short8 wh[2][2], wl[2][2];
    #pragma unroll
    for (int kt = 0; kt < 2; ++kt) {
        const int krow = (2 * w + kt) * 16 + l15;
        #pragma unroll
        for (int ks = 0; ks < 2; ++ks) {
            const float4* wp = (const float4*)(conv_w + krow * CDIM + ks * 32 + l4 * 8);
            float4 wa = wp[0], wb = wp[1];
            float wv[8] = {wa.x, wa.y, wa.z, wa.w, wb.x, wb.y, wb.z, wb.w};
            #pragma unroll
            for (int j = 0; j < 8; ++j) {
                unsigned u = __builtin_bit_cast(unsigned, wv[j]);
                wh[kt][ks][j] = (short)(u >> 16);
                float hf = __builtin_bit_cast(float, u & 0xffff0000u);
                wl[kt][ks][j] = (short)(__builtin_bit_cast(unsigned, wv[j] - hf) >> 16);
            }
        }
    }
    // bias per D-row (k = (2w+kt)*16 + l4*4 + i), pre-shifted
    float cbr[2][4];
    #pragma unroll
    for (int kt = 0; kt < 2; ++kt)
        #pragma unroll
        for (int i = 0; i < 4; ++i)
            cbr[kt][i] = conv_b[(2 * w + kt) * 16 + l4 * 4 + i] - SHIFT;

    f32x4 acc2[2][4];                   // V tiles [kt][ct]
    #pragma unroll
    for (int a = 0; a < 2; ++a)
        #pragma unroll
        for (int b = 0; b < 4; ++b) acc2[a][b] = (f32x4)0.0f;
    float asr[2][4];                    // asum partials per D-row
    #pragma unroll
    for (int a = 0; a < 2; ++a)
        #pragma unroll
        for (int i = 0; i < 4; ++i) asr[a][i] = 0.f;

    const float* xbase = x + (size_t)n * CDIM * HWPX + part * PIXPART;

    float xv0[8], xv1[8];               // pixel p0 / p1 = p0+16

    // pipeline carry: chunk-j softmax numerators + 1/||x|| (consumed at j+1)
    float e[2][4][4];
    float rnv[4];

    #define LOADX(OFF) do {                                                 \
        _Pragma("unroll")                                                   \
        for (int j = 0; j < 8; ++j) {                                       \
            xv0[j] = xbase[(sg * 8 + j) * HWPX + (OFF) + p0];               \
            xv1[j] = xbase[(sg * 8 + j) * HWPX + (OFF) + p0 + 16];          \
        }                                                                   \
    } while (0)

    // stage: ssq pair + xp hi/lo rows (p0,p1) + xc plane into buffer `buf`.
    auto stage = [&](int buf) {
        float ssq0 = 0.f, ssq1 = 0.f;
        #pragma unroll
        for (int j = 0; j < 8; ++j) {
            ssq0 += xv0[j] * xv0[j];
            ssq1 += xv1[j] * xv1[j];
        }
        ssq0 += __shfl_xor(ssq0, 32);   // combine the wave's 2 sg's
        ssq1 += __shfl_xor(ssq1, 32);
        if (l < 32) redA2[buf][w * 32 + q] = make_float2(ssq0, ssq1);

        // xp row p0 (from xv0)
        {
            unsigned uh[4], ul[4];
            #pragma unroll
            for (int jp = 0; jp < 4; ++jp) {
                const unsigned u0 = __builtin_bit_cast(unsigned, xv0[2 * jp]);
                const unsigned u1 = __builtin_bit_cast(unsigned, xv0[2 * jp + 1]);
                uh[jp] = __builtin_amdgcn_perm(u1, u0, PERM_HI16);
                const float h0 = __builtin_bit_cast(float, u0 & 0xffff0000u);
                const float h1 = __builtin_bit_cast(float, u1 & 0xffff0000u);
                const unsigned lo0 = __builtin_bit_cast(unsigned, xv0[2 * jp] - h0);
                const unsigned lo1 = __builtin_bit_cast(unsigned, xv0[2 * jp + 1] - h1);
                ul[jp] = __builtin_amdgcn_perm(lo1, lo0, PERM_HI16);
            }
            *(uint4*)&xp_hi[buf][p0 * XP_S + sg * 8] = make_uint4(uh[0], uh[1], uh[2], uh[3]);
            *(uint4*)&xp_lo[buf][p0 * XP_S + sg * 8] = make_uint4(ul[0], ul[1], ul[2], ul[3]);
        }
        // xp row p1 (from xv1)
        {
            unsigned uh[4], ul[4];
            #pragma unroll
            for (int jp = 0; jp < 4; ++jp) {
                const unsigned u0 = __builtin_bit_cast(unsigned, xv1[2 * jp]);
                const unsigned u1 = __builtin_bit_cast(unsigned, xv1[2 * jp + 1]);
                uh[jp] = __builtin_amdgcn_perm(u1, u0, PERM_HI16);
                const float h0 = __builtin_bit_cast(float, u0 & 0xffff0000u);
                const float h1 = __builtin_bit_cast(float, u1 & 0xffff0000u);
                const unsigned lo0 = __builtin_bit_cast(unsigned, xv1[2 * jp] - h0);
                const unsigned lo1 = __builtin_bit_cast(unsigned, xv1[2 * jp + 1] - h1);
                ul[jp] = __builtin_amdgcn_perm(lo1, lo0, PERM_HI16);
            }
            *(uint4*)&xp_hi[buf][(p0 + 16) * XP_S + sg * 8] = make_uint4(uh[0], uh[1], uh[2], uh[3]);
            *(uint4*)&xp_lo[buf][(p0 + 16) * XP_S + sg * 8] = make_uint4(ul[0], ul[1], ul[2], ul[3]);
        }

        // xc plane (RNE bf16): pair (p0, p0+16) -> one b32 at (xslot, +1).
        #pragma unroll
        for (int j = 0; j < 8; ++j) {
            unsigned pk;
            asm("v_cvt_pk_bf16_f32 %0, %1, %2"
                : "=v"(pk) : "v"(xv0[j]), "v"(xv1[j]));
            *(unsigned*)&xc[buf][(sg * 8 + j) * XC_S + xslot] = pk;
        }
    };

    // mm1 + softmax numerators for chunk with buffer parity b; fills e, rnv,
    // and writes this chunk's sumP2[b] (visible after the following BAR).
    auto mm1_sec = [&](int b) {
        f32x4 a1[2][4];
        #pragma unroll
        for (int a = 0; a < 2; ++a)
            #pragma unroll
            for (int c = 0; c < 4; ++c) a1[a][c] = (f32x4)0.0f;
        #pragma unroll
        for (int ks = 0; ks < 2; ++ks) {
            #pragma unroll
            for (int pt = 0; pt < 4; ++pt) {
                short8 bh = *(short8*)&xp_hi[b][(pt * 16 + l15) * XP_S + ks * 32 + l4 * 8];
                short8 bl = *(short8*)&xp_lo[b][(pt * 16 + l15) * XP_S + ks * 32 + l4 * 8];
                #pragma unroll
                for (int kt = 0; kt < 2; ++kt) {
                    a1[kt][pt] = MFMA(wh[kt][ks], bh, a1[kt][pt]);
                    a1[kt][pt] = MFMA(wh[kt][ks], bl, a1[kt][pt]);
                    a1[kt][pt] = MFMA(wl[kt][ks], bh, a1[kt][pt]);
                }
            }
        }

        // per-column 1/||x||
        float2 ra0 = redA2[b][l15],           ra1 = redA2[b][32 + l15];
        float2 ra2 = redA2[b][64 + l15],      ra3 = redA2[b][96 + l15];
        float2 rb0 = redA2[b][16 + l15],      rb1 = redA2[b][48 + l15];
        float2 rb2 = redA2[b][80 + l15],      rb3 = redA2[b][112 + l15];
        rnv[0] = 1.0f / fmaxf(sqrtf((ra0.x + ra1.x) + (ra2.x + ra3.x)), 1e-12f);
        rnv[1] = 1.0f / fmaxf(sqrtf((ra0.y + ra1.y) + (ra2.y + ra3.y)), 1e-12f);
        rnv[2] = 1.0f / fmaxf(sqrtf((rb0.x + rb1.x) + (rb2.x + rb3.x)), 1e-12f);
        rnv[3] = 1.0f / fmaxf(sqrtf((rb0.y + rb1.y) + (rb2.y + rb3.y)), 1e-12f);

        // in-register softmax numerators (no max pass; bias pre-shifted)
        float sp[4] = {0.f, 0.f, 0.f, 0.f};
        #pragma unroll
        for (int kt = 0; kt < 2; ++kt)
            #pragma unroll
            for (int pt = 0; pt < 4; ++pt)
                #pragma unroll
                for (int i = 0; i < 4; ++i) {
                    float ev = __expf(fmaf(a1[kt][pt][i], rnv[pt], cbr[kt][i]));
                    e[kt][pt][i] = ev;
                    sp[pt] += ev;
                }
        #pragma unroll
        for (int pt = 0; pt < 4; ++pt) {
            sp[pt] += __shfl_xor(sp[pt], 16);
            sp[pt] += __shfl_xor(sp[pt], 32);   // wave-sum over its 32 k's
        }
        if (l4 == 0)      sumP2[b][w * 32 + l15]      = make_float2(sp[0], sp[1]);
        else if (l4 == 1) sumP2[b][w * 32 + 16 + l15] = make_float2(sp[2], sp[3]);
    };

    // ph + mm2 for the chunk with buffer parity pb (its sumP2/xc), consuming
    // the carried e/rnv. Runs one iteration after mm1_sec(pb).
    auto ph_mm2 = [&](int pb) {
        float2 q0 = sumP2[pb][l15],       q1 = sumP2[pb][32 + l15];
        float2 q2 = sumP2[pb][64 + l15],  q3 = sumP2[pb][96 + l15];
        float2 r0 = sumP2[pb][16 + l15],  r1 = sumP2[pb][48 + l15];
        float2 r2 = sumP2[pb][80 + l15],  r3 = sumP2[pb][112 + l15];
        float rden[4], rdn2[4];
        rden[0] = 1.0f / ((q0.x + q1.x) + (q2.x + q3.x));
        rden[1] = 1.0f / ((q0.y + q1.y) + (q2.y + q3.y));
        rden[2] = 1.0f / ((r0.x + r1.x) + (r2.x + r3.x));
        rden[3] = 1.0f / ((r0.y + r1.y) + (r2.y + r3.y));
        #pragma unroll
        for (int pt = 0; pt < 4; ++pt) rdn2[pt] = rden[pt] * rnv[pt];

        // P' -> ph: two b32 per (kt,i): slots (2l15,2l15+1), (+32)
        #pragma unroll
        for (int kt = 0; kt < 2; ++kt)
            #pragma unroll
            for (int i = 0; i < 4; ++i) {
                const int row = (2 * w + kt) * 16 + l4 * 4 + i;
                const float e0 = e[kt][0][i], e1 = e[kt][1][i];
                const float e2 = e[kt][2][i], e3 = e[kt][3][i];
                asr[kt][i] = fmaf(e0, rden[0], asr[kt][i]);
                asr[kt][i] = fmaf(e1, rden[1], asr[kt][i]);
                asr[kt][i] = fmaf(e2, rden[2], asr[kt][i]);
                asr[kt][i] = fmaf(e3, rden[3], asr[kt][i]);
                const float p0f = e0 * rdn2[0], p1f = e1 * rdn2[1];
                const float p2f = e2 * rdn2[2], p3f = e3 * rdn2[3];
                unsigned pk01, pk23;
                asm("v_cvt_pk_bf16_f32 %0, %1, %2" : "=v"(pk01) : "v"(p0f), "v"(p1f));
                asm("v_cvt_pk_bf16_f32 %0, %1, %2" : "=v"(pk23) : "v"(p2f), "v"(p3f));
                *(unsigned*)&ph[row * PH_S + 2 * l15]      = pk01;
                *(unsigned*)&ph[row * PH_S + 32 + 2 * l15] = pk23;
            }
        // no barrier: mm2 reads only the ph rows this wave just wrote.

        // mm2: V[k][c] += P' @ Xc^T (kdim = 64 interleaved slots)
        short8 xh2[4][2];
        #pragma unroll
        for (int ct = 0; ct < 4; ++ct)
            #pragma unroll
            for (int hh = 0; hh < 2; ++hh)
                xh2[ct][hh] = *(short8*)&xc[pb][(ct * 16 + l15) * XC_S + hh * 32 + l4 * 8];
        #pragma unroll
        for (int kt = 0; kt < 2; ++kt) {
            short8 ah0 = *(short8*)&ph[((2 * w + kt) * 16 + l15) * PH_S + l4 * 8];
            short8 ah1 = *(short8*)&ph[((2 * w + kt) * 16 + l15) * PH_S + 32 + l4 * 8];
            #pragma unroll
            for (int ct = 0; ct < 4; ++ct) {
                acc2[kt][ct] = MFMA(ah0, xh2[ct][0], acc2[kt][ct]);
                acc2[kt][ct] = MFMA(ah1, xh2[ct][1], acc2[kt][ct]);
            }
        }
    };

    // ---- prologue --------------------------------------------------------
    LOADX(0);
    stage(0);
    if (NCHUNK > 1) LOADX(TL);
    BAR();                               // stage(0) visible
    if (NCHUNK > 1) stage(1);
    if (NCHUNK > 2) LOADX(2 * TL);
    mm1_sec(0);
    BAR();                               // sumP2[0] + stage(1) visible

    // ---- main pipeline ---------------------------------------------------
    for (int ch = 1; ch < NCHUNK; ++ch) {
        ph_mm2((ch - 1) & 1);            // finish chunk ch-1
        BAR();                           // BAR_a: xc[(ch-1)&1] reads done
        if (ch + 1 < NCHUNK) stage((ch + 1) & 1);
        if (ch + 2 < NCHUNK) LOADX((ch + 2) * TL);
        mm1_sec(ch & 1);                 // chunk ch numerators
        BAR();                           // BAR_b: sumP2[ch&1] + stage visible
    }
    ph_mm2((NCHUNK - 1) & 1);            // epilogue: finish last chunk
    #undef LOADX

    // ---- V accumulate: device-scope atomicAdd (coherent, L2 stays clean) --
    float* vg = vacc + (size_t)n * KCL * CDIM;
    #pragma unroll
    for (int kt = 0; kt < 2; ++kt)
        #pragma unroll
        for (int ct = 0; ct < 4; ++ct)
            #pragma unroll
            for (int i = 0; i < 4; ++i) {
                const int row = (2 * w + kt) * 16 + l4 * 4 + i;
                const int col = ct * 16 + l15;
                atomicAdd(&vg[row * CDIM + col], acc2[kt][ct][i]);
            }

    // ---- asum: reduce over l15 lanes, lane0-of-16 atomicAdds --------------
    #pragma unroll
    for (int kt = 0; kt < 2; ++kt)
        #pragma unroll
        for (int i = 0; i < 4; ++i) {
            float v = asr[kt][i];
            v += __shfl_xor(v, 1); v += __shfl_xor(v, 2);
            v += __shfl_xor(v, 4); v += __shfl_xor(v, 8);
            if (l15 == 0) {
                const int row = (2 * w + kt) * 16 + l4 * 4 + i;
                atomicAdd(&asacc[n * KCL + row], v);
            }
        }

    if (!FUSED) return;

    // ---- fused finalize: last block of image n normalizes -----------------
    __syncthreads();                 // vmcnt(0): all atomics complete
    __shared__ int lastFlag;
    if (t == 0) {
        int prev = __hip_atomic_fetch_add(&counters[n], 1,
                                          __ATOMIC_ACQ_REL,
                                          __HIP_MEMORY_SCOPE_AGENT);
        lastFlag = (prev == NP - 1) ? 1 : 0;
    }
    __syncthreads();
    if (!lastFlag) return;
    __threadfence();                 // acquire/inv: plain loads see atomics
                                     // (L2 clean -> writeback part ~free)

    const int kk = t >> 4;           // 0..15
    const int c0 = (t & 15) * 4;
    const float* va = vacc + (size_t)n * KCL * CDIM;
    const float* aa = asacc + n * KCL;
    #pragma unroll
    for (int kg = 0; kg < 8; ++kg) {
        const int k = kg * 16 + kk;
        float4 a = *(const float4*)(va + k * CDIM + c0);
        float vs[4] = {a.x, a.y, a.z, a.w};
        const float av = aa[k];
        float4 cq = *(const float4*)(cent + k * CDIM + c0);
        float cc[4] = {cq.x, cq.y, cq.z, cq.w};
        float ss = 0.f;
        #pragma unroll
        for (int j = 0; j < 4; ++j) {
            vs[j] -= av * cc[j];
            ss += vs[j] * vs[j];
        }
        ss += __shfl_xor(ss, 1); ss += __shfl_xor(ss, 2);
        ss += __shfl_xor(ss, 4); ss += __shfl_xor(ss, 8);
        const float s = (1.0f / fmaxf(sqrtf(ss), 1e-12f)) * RSQRT128;
        float4 o;
        o.x = vs[0] * s; o.y = vs[1] * s; o.z = vs[2] * s; o.w = vs[3] * s;
        *(float4*)(outp + (size_t)n * KCL * CDIM + k * CDIM + c0) = o;
    }
}

// ---------------------------------------------------------------------------
// Kernel 2 (FALLBACK tier only): normalize the atomic accumulators.
// ---------------------------------------------------------------------------
__global__ __launch_bounds__(256)
void netvlad_finalize(const float* __restrict__ vacc,    // [N][K][C]
                      const float* __restrict__ asacc,   // [N][K]
                      const float* __restrict__ cent,    // [K][C]
                      float* __restrict__ out)           // [N][K*C]
{
    const int t = threadIdx.x;
    const int n  = blockIdx.x >> 3;
    const int kg = blockIdx.x & 7;
    const int k  = kg * 16 + (t >> 4);
    const int c0 = (t & 15) * 4;

    float4 a = *(const float4*)(vacc + ((size_t)n * KCL + k) * CDIM + c0);
    float vsum[4] = {a.x, a.y, a.z, a.w};
    const float av = asacc[n * KCL + k];

    float4 cq = *(const float4*)(cent + k * CDIM + c0);
    float cc[4] = {cq.x, cq.y, cq.z, cq.w};
    float ss = 0.f;
    #pragma unroll
    for (int j = 0; j < 4; ++j) {
        vsum[j] -= av * cc[j];
        ss += vsum[j] * vsum[j];
    }
    ss += __shfl_xor(ss, 1); ss += __shfl_xor(ss, 2);
    ss += __shfl_xor(ss, 4); ss += __shfl_xor(ss, 8);
    const float s = (1.0f / fmaxf(sqrtf(ss), 1e-12f)) * RSQRT128;

    float4 o;
    o.x = vsum[0] * s; o.y = vsum[1] * s; o.z = vsum[2] * s; o.w = vsum[3] * s;
    *(float4*)(out + (size_t)n * KCL * CDIM + k * CDIM + c0) = o;
}

// ---------------------------------------------------------------------------
extern "C" void kernel_launch(void* const* d_in, const int* in_sizes, int n_in,
                              void* d_out, int out_size, void* d_ws, size_t ws_size,
                              hipStream_t stream) {
    const float* x     = (const float*)d_in[0];   // [64,64,64,64]
    const float* cent  = (const float*)d_in[1];   // [128,64]
    const float* convw = (const float*)d_in[2];   // [128,64]
    const float* convb = (const float*)d_in[3];   // [128]
    float* out = (float*)d_out;

    // Layout: [0,1KB) counters (64 ints), then vacc [N][K][C], asacc [N][K].
    const size_t accf = (size_t)NIMG * (KCL * CDIM + KCL);
    const size_t need = 1024 + accf * sizeof(float);    // ~2.13 MB

    int*   counters = (int*)d_ws;
    float* vacc  = (float*)((char*)d_ws + 1024);
    float* asacc = vacc + (size_t)NIMG * KCL * CDIM;

    if (ws_size >= need) {
        hipMemsetAsync(d_ws, 0, need, stream);          // counters + accs
        netvlad_main<8, 1><<<dim3(NIMG * 8), dim3(256), 0, stream>>>(
            x, convw, convb, cent, vacc, asacc, counters, out);
    } else {
        // ws too small even for accumulators: two-kernel atomic fallback
        hipMemsetAsync(d_ws, 0, ws_size < need ? ws_size : need, stream);
        netvlad_main<8, 0><<<dim3(NIMG * 8), dim3(256), 0, stream>>>(
            x, convw, convb, cent, vacc, asacc, nullptr, out);
        netvlad_finalize<<<dim3(NIMG * 8), dim3(256), 0, stream>>>(
            vacc, asacc, cent, out);
    }
}

// Round 13
// 121.368 us; speedup vs baseline: 1.4564x; 1.2548x over previous
//
#include <hip/hip_runtime.h>
#include <math.h>

// Problem constants (fixed by the reference setup_inputs)
#define NIMG   64
#define CDIM   64
#define HWPX   4096
#define KCL    128
#define TL     64                // pixels per chunk
#define SHIFT  10.0f             // softmax shift folded into bias
#define RSQRT128 0.08838834764831845f

// LDS strides in shorts (multiples of 8 so b128 stays 16B-aligned)
#define XP_S 72    // xp planes [64 p][64 c]
#define XC_S 72    // xc plane  [64 c][64 slot]
#define PH_S 72    // ph plane  [128 k][64 slot]

typedef __attribute__((ext_vector_type(8))) short short8; // 8 bf16
typedef __attribute__((ext_vector_type(4))) float f32x4;  // MFMA C/D

#define MFMA(a, b, c) __builtin_amdgcn_mfma_f32_16x16x32_bf16((a), (b), (c), 0, 0, 0)

// Pack the truncated-bf16 prefixes of two floats into one u32 with a single
// v_perm_b32: bytes {f0.b2, f0.b3, f1.b2, f1.b3}.
#define PERM_HI16 0x07060302u

// Relaxed workgroup barrier: LDS-visibility only (no vmcnt(0) drain, so the
// global prefetch stays in flight across the barrier).
#define BAR() do {                                          \
    asm volatile("s_waitcnt lgkmcnt(0)" ::: "memory");      \
    __builtin_amdgcn_s_barrier();                           \
    __builtin_amdgcn_sched_barrier(0);                      \
} while (0)

// ---------------------------------------------------------------------------
// R23 = REVERT to R17, the session's best-measured configuration
// (e2e 122.8us, main 41.8us).
//
// FULL HISTORY (measured):
// R11 FAIL  launch_bounds(256,4) -> VGPR 64 -> spills, 2.1x slower.
// R12 NEUT  NP=16 (4 blocks/CU): extra waves don't help.
// R13 NEUT  VALU-lean conversions: VALUBusy 37->33%, time flat.
// R14 REGR  staging remap: +conflicts, 64B loads, shfl=DS.
// R15 WIN   stage dbuf, 3->2 barriers/chunk: 45.8->44.0.
// R16 NULL  small-DS-op cuts under noise.
// R17 WIN   TL=64 (8 chunks, 16 barriers): 44.0->41.8. *** BEST ***
// R18 REGR  2x2 k/pixel wave partition: conflicts 1.84M->3.1M.
// R20 NEUT  softmax-tail software pipeline: 42.2 (= R17 within noise).
// R21 REGR  fused finalize, partial STORES + per-block __threadfence:
//           main 120us (dirty-L2 writeback per release fence x512).
// R22 REGR  fused finalize, device-scope atomicAdd accumulation:
//           main 111us (~4.2M coherent RMW atomics ~ 17ns each).
//
// CONCLUSIONS: main kernel is on a latency plateau (~42us; no pipe >40%;
// only barrier-structure cuts ever moved time, now exhausted). The
// finalize+launch (~25us) resisted two mechanistically-distinct fusion
// designs -- both regressions are structural (XCD-noncoherent L2: release
// fences force writeback; coherent RMW serializes at the far point). The
// remaining ~56us of e2e-main gap is harness-fixed (constant over 13 runs).
// ---------------------------------------------------------------------------
template <int NP>
__global__ __launch_bounds__(256, 2)
void netvlad_main(const float* __restrict__ x,       // [N][C][HW]
                  const float* __restrict__ conv_w,  // [K][C]
                  const float* __restrict__ conv_b,  // [K]
                  float* __restrict__ vout,          // partials or atomic acc
                  float* __restrict__ asout,
                  int use_atomic)
{
    constexpr int PIXPART = HWPX / NP;   // pixels per block (512)
    constexpr int NCHUNK  = PIXPART / TL;  // 8

    __shared__ __align__(16) short xp_hi[2][TL * XP_S], xp_lo[2][TL * XP_S]; // 36.9 KB
    __shared__ __align__(16) short xc[2][CDIM * XC_S];                       // 18.4 KB
    __shared__ __align__(16) short ph[KCL * PH_S];                           // 18.4 KB
    __shared__ __align__(8) float2 redA2[2][4 * 32];  // ssq pairs [buf][wave][q]
    __shared__ __align__(8) float2 sumP2[4 * 32];     // exp-sum pairs [wave][2*16]

    const int t   = threadIdx.x;
    const int w   = t >> 6;             // wave 0..3
    const int l   = t & 63;
    const int l15 = l & 15, l4 = l >> 4;
    const int n    = blockIdx.x / NP;
    const int part = blockIdx.x - n * NP;
    const int q    = t & 31;            // staging pixel-pair id
    const int sg   = t >> 5;            // staging c-group (8 c's)
    const int p0   = (q & 15) + ((q & 16) << 1);   // 0..15, 32..47
    // p1 = p0 + 16
    const int xslot = ((q >> 4) << 5) + 2 * (q & 15);  // kdim slot of p0 (even)

    // ---- W fragments in registers (once): A[m=k][kdim=c], 3-term split ----
    short8 wh[2][2], wl[2][2];
    #pragma unroll
    for (int kt = 0; kt < 2; ++kt) {
        const int krow = (2 * w + kt) * 16 + l15;
        #pragma unroll
        for (int ks = 0; ks < 2; ++ks) {
            const float4* wp = (const float4*)(conv_w + krow * CDIM + ks * 32 + l4 * 8);
            float4 wa = wp[0], wb = wp[1];
            float wv[8] = {wa.x, wa.y, wa.z, wa.w, wb.x, wb.y, wb.z, wb.w};
            #pragma unroll
            for (int j = 0; j < 8; ++j) {
                unsigned u = __builtin_bit_cast(unsigned, wv[j]);
                wh[kt][ks][j] = (short)(u >> 16);
                float hf = __builtin_bit_cast(float, u & 0xffff0000u);
                wl[kt][ks][j] = (short)(__builtin_bit_cast(unsigned, wv[j] - hf) >> 16);
            }
        }
    }
    // bias per D-row (k = (2w+kt)*16 + l4*4 + i), pre-shifted
    float cbr[2][4];
    #pragma unroll
    for (int kt = 0; kt < 2; ++kt)
        #pragma unroll
        for (int i = 0; i < 4; ++i)
            cbr[kt][i] = conv_b[(2 * w + kt) * 16 + l4 * 4 + i] - SHIFT;

    f32x4 acc2[2][4];                   // V tiles [kt][ct]
    #pragma unroll
    for (int a = 0; a < 2; ++a)
        #pragma unroll
        for (int b = 0; b < 4; ++b) acc2[a][b] = (f32x4)0.0f;
    float asr[2][4];                    // asum partials per D-row
    #pragma unroll
    for (int a = 0; a < 2; ++a)
        #pragma unroll
        for (int i = 0; i < 4; ++i) asr[a][i] = 0.f;

    const float* xbase = x + (size_t)n * CDIM * HWPX + part * PIXPART;

    float xv0[8], xv1[8];               // pixel p0 / p1 = p0+16

    #define LOADX(OFF) do {                                                 \
        _Pragma("unroll")                                                   \
        for (int j = 0; j < 8; ++j) {                                       \
            xv0[j] = xbase[(sg * 8 + j) * HWPX + (OFF) + p0];               \
            xv1[j] = xbase[(sg * 8 + j) * HWPX + (OFF) + p0 + 16];          \
        }                                                                   \
    } while (0)

    // stage: ssq pair + xp hi/lo rows (p0,p1) + xc plane into buffer `buf`.
    auto stage = [&](int buf) {
        float ssq0 = 0.f, ssq1 = 0.f;
        #pragma unroll
        for (int j = 0; j < 8; ++j) {
            ssq0 += xv0[j] * xv0[j];
            ssq1 += xv1[j] * xv1[j];
        }
        ssq0 += __shfl_xor(ssq0, 32);   // combine the wave's 2 sg's
        ssq1 += __shfl_xor(ssq1, 32);
        if (l < 32) redA2[buf][w * 32 + q] = make_float2(ssq0, ssq1);

        // xp row p0 (from xv0)
        {
            unsigned uh[4], ul[4];
            #pragma unroll
            for (int jp = 0; jp < 4; ++jp) {
                const unsigned u0 = __builtin_bit_cast(unsigned, xv0[2 * jp]);
                const unsigned u1 = __builtin_bit_cast(unsigned, xv0[2 * jp + 1]);
                uh[jp] = __builtin_amdgcn_perm(u1, u0, PERM_HI16);
                const float h0 = __builtin_bit_cast(float, u0 & 0xffff0000u);
                const float h1 = __builtin_bit_cast(float, u1 & 0xffff0000u);
                const unsigned lo0 = __builtin_bit_cast(unsigned, xv0[2 * jp] - h0);
                const unsigned lo1 = __builtin_bit_cast(unsigned, xv0[2 * jp + 1] - h1);
                ul[jp] = __builtin_amdgcn_perm(lo1, lo0, PERM_HI16);
            }
            *(uint4*)&xp_hi[buf][p0 * XP_S + sg * 8] = make_uint4(uh[0], uh[1], uh[2], uh[3]);
            *(uint4*)&xp_lo[buf][p0 * XP_S + sg * 8] = make_uint4(ul[0], ul[1], ul[2], ul[3]);
        }
        // xp row p1 (from xv1)
        {
            unsigned uh[4], ul[4];
            #pragma unroll
            for (int jp = 0; jp < 4; ++jp) {
                const unsigned u0 = __builtin_bit_cast(unsigned, xv1[2 * jp]);
                const unsigned u1 = __builtin_bit_cast(unsigned, xv1[2 * jp + 1]);
                uh[jp] = __builtin_amdgcn_perm(u1, u0, PERM_HI16);
                const float h0 = __builtin_bit_cast(float, u0 & 0xffff0000u);
                const float h1 = __builtin_bit_cast(float, u1 & 0xffff0000u);
                const unsigned lo0 = __builtin_bit_cast(unsigned, xv1[2 * jp] - h0);
                const unsigned lo1 = __builtin_bit_cast(unsigned, xv1[2 * jp + 1] - h1);
                ul[jp] = __builtin_amdgcn_perm(lo1, lo0, PERM_HI16);
            }
            *(uint4*)&xp_hi[buf][(p0 + 16) * XP_S + sg * 8] = make_uint4(uh[0], uh[1], uh[2], uh[3]);
            *(uint4*)&xp_lo[buf][(p0 + 16) * XP_S + sg * 8] = make_uint4(ul[0], ul[1], ul[2], ul[3]);
        }

        // xc plane (RNE bf16): pair (p0, p0+16) packs into one b32 at slots
        // (xslot, xslot+1).
        #pragma unroll
        for (int j = 0; j < 8; ++j) {
            unsigned pk;
            asm("v_cvt_pk_bf16_f32 %0, %1, %2"
                : "=v"(pk) : "v"(xv0[j]), "v"(xv1[j]));
            *(unsigned*)&xc[buf][(sg * 8 + j) * XC_S + xslot] = pk;
        }
    };

    // ---- prologue: stage chunk 0, prefetch chunk 1 ------------------------
    LOADX(0);
    stage(0);
    if (NCHUNK > 1) LOADX(TL);
    BAR();

    for (int ch = 0; ch < NCHUNK; ++ch) {
        const int cur = ch & 1;

        // ---- stage next chunk into the other buffer (overlaps compute) ---
        if (ch + 1 < NCHUNK) {
            stage(cur ^ 1);
            if (ch + 2 < NCHUNK) LOADX((ch + 2) * TL);
        }

        // ---- mm1: a1[kt][pt] = W @ Xraw  (3-term split), pt = 4 tiles -----
        f32x4 a1[2][4];
        #pragma unroll
        for (int a = 0; a < 2; ++a)
            #pragma unroll
            for (int b = 0; b < 4; ++b) a1[a][b] = (f32x4)0.0f;
        #pragma unroll
        for (int ks = 0; ks < 2; ++ks) {
            #pragma unroll
            for (int pt = 0; pt < 4; ++pt) {
                short8 bh = *(short8*)&xp_hi[cur][(pt * 16 + l15) * XP_S + ks * 32 + l4 * 8];
                short8 bl = *(short8*)&xp_lo[cur][(pt * 16 + l15) * XP_S + ks * 32 + l4 * 8];
                #pragma unroll
                for (int kt = 0; kt < 2; ++kt) {
                    a1[kt][pt] = MFMA(wh[kt][ks], bh, a1[kt][pt]);
                    a1[kt][pt] = MFMA(wh[kt][ks], bl, a1[kt][pt]);
                    a1[kt][pt] = MFMA(wl[kt][ks], bh, a1[kt][pt]);
                }
            }
        }

        // ---- per-column 1/||x||: 8 b64 reads ------------------------------
        float2 ra0 = redA2[cur][l15],           ra1 = redA2[cur][32 + l15];
        float2 ra2 = redA2[cur][64 + l15],      ra3 = redA2[cur][96 + l15];
        float2 rb0 = redA2[cur][16 + l15],      rb1 = redA2[cur][48 + l15];
        float2 rb2 = redA2[cur][80 + l15],      rb3 = redA2[cur][112 + l15];
        float rn[4];
        rn[0] = 1.0f / fmaxf(sqrtf((ra0.x + ra1.x) + (ra2.x + ra3.x)), 1e-12f);
        rn[1] = 1.0f / fmaxf(sqrtf((ra0.y + ra1.y) + (ra2.y + ra3.y)), 1e-12f);
        rn[2] = 1.0f / fmaxf(sqrtf((rb0.x + rb1.x) + (rb2.x + rb3.x)), 1e-12f);
        rn[3] = 1.0f / fmaxf(sqrtf((rb0.y + rb1.y) + (rb2.y + rb3.y)), 1e-12f);

        // ---- in-register softmax over k (no max pass; bias pre-shifted) ---
        float e[2][4][4], sp[4] = {0.f, 0.f, 0.f, 0.f};
        #pragma unroll
        for (int kt = 0; kt < 2; ++kt)
            #pragma unroll
            for (int pt = 0; pt < 4; ++pt)
                #pragma unroll
                for (int i = 0; i < 4; ++i) {
                    float ev = __expf(fmaf(a1[kt][pt][i], rn[pt], cbr[kt][i]));
                    e[kt][pt][i] = ev;
                    sp[pt] += ev;
                }
        #pragma unroll
        for (int pt = 0; pt < 4; ++pt) {
            sp[pt] += __shfl_xor(sp[pt], 16);
            sp[pt] += __shfl_xor(sp[pt], 32);     // wave-sum over its 32 k's
        }
        if (l4 == 0)      sumP2[w * 32 + l15]      = make_float2(sp[0], sp[1]);
        else if (l4 == 1) sumP2[w * 32 + 16 + l15] = make_float2(sp[2], sp[3]);
        BAR();                                            // bar 1: sumP done

        float2 q0 = sumP2[l15],       q1 = sumP2[32 + l15];
        float2 q2 = sumP2[64 + l15],  q3 = sumP2[96 + l15];
        float2 r0 = sumP2[16 + l15],  r1 = sumP2[48 + l15];
        float2 r2 = sumP2[80 + l15],  r3 = sumP2[112 + l15];
        float rden[4], rdn2[4];
        rden[0] = 1.0f / ((q0.x + q1.x) + (q2.x + q3.x));
        rden[1] = 1.0f / ((q0.y + q1.y) + (q2.y + q3.y));
        rden[2] = 1.0f / ((r0.x + r1.x) + (r2.x + r3.x));
        rden[3] = 1.0f / ((r0.y + r1.y) + (r2.y + r3.y));
        #pragma unroll
        for (int pt = 0; pt < 4; ++pt) rdn2[pt] = rden[pt] * rn[pt];

        // ---- P' -> ph: two b32 per (kt,i): slots (2l15,2l15+1), (+32) -----
        #pragma unroll
        for (int kt = 0; kt < 2; ++kt)
            #pragma unroll
            for (int i = 0; i < 4; ++i) {
                const int row = (2 * w + kt) * 16 + l4 * 4 + i;
                const float e0 = e[kt][0][i], e1 = e[kt][1][i];
                const float e2 = e[kt][2][i], e3 = e[kt][3][i];
                asr[kt][i] = fmaf(e0, rden[0], asr[kt][i]);
                asr[kt][i] = fmaf(e1, rden[1], asr[kt][i]);
                asr[kt][i] = fmaf(e2, rden[2], asr[kt][i]);
                asr[kt][i] = fmaf(e3, rden[3], asr[kt][i]);
                const float p0f = e0 * rdn2[0], p1f = e1 * rdn2[1];
                const float p2f = e2 * rdn2[2], p3f = e3 * rdn2[3];
                unsigned pk01, pk23;
                asm("v_cvt_pk_bf16_f32 %0, %1, %2" : "=v"(pk01) : "v"(p0f), "v"(p1f));
                asm("v_cvt_pk_bf16_f32 %0, %1, %2" : "=v"(pk23) : "v"(p2f), "v"(p3f));
                *(unsigned*)&ph[row * PH_S + 2 * l15]      = pk01;
                *(unsigned*)&ph[row * PH_S + 32 + 2 * l15] = pk23;
            }
        // no barrier: mm2 reads only the ph rows this wave just wrote
        // (intra-wave LDS ordering is guaranteed).

        // ---- mm2: V[k][c] += P' @ Xraw^T (kdim = 64 interleaved slots) ----
        {
            short8 xh2[4][2];
            #pragma unroll
            for (int ct = 0; ct < 4; ++ct)
                #pragma unroll
                for (int h = 0; h < 2; ++h)
                    xh2[ct][h] = *(short8*)&xc[cur][(ct * 16 + l15) * XC_S + h * 32 + l4 * 8];
            #pragma unroll
            for (int kt = 0; kt < 2; ++kt) {
                short8 ah0 = *(short8*)&ph[((2 * w + kt) * 16 + l15) * PH_S + l4 * 8];
                short8 ah1 = *(short8*)&ph[((2 * w + kt) * 16 + l15) * PH_S + 32 + l4 * 8];
                #pragma unroll
                for (int ct = 0; ct < 4; ++ct) {
                    acc2[kt][ct] = MFMA(ah0, xh2[ct][0], acc2[kt][ct]);
                    acc2[kt][ct] = MFMA(ah1, xh2[ct][1], acc2[kt][ct]);
                }
            }
        }
        BAR();   // bar 2: chunk end (protects buf[cur] for restage,
                 // sumP2 for next write, ph for next write)
    }
    #undef LOADX

    // ---- V write (coalesced: lanes l15 -> consecutive c) ------------------
    float* vg = use_atomic ? vout + (size_t)n * KCL * CDIM
                           : vout + (size_t)blockIdx.x * KCL * CDIM;
    #pragma unroll
    for (int kt = 0; kt < 2; ++kt)
        #pragma unroll
        for (int ct = 0; ct < 4; ++ct)
            #pragma unroll
            for (int i = 0; i < 4; ++i) {
                const int row = (2 * w + kt) * 16 + l4 * 4 + i;
                const int col = ct * 16 + l15;
                if (use_atomic) atomicAdd(&vg[row * CDIM + col], acc2[kt][ct][i]);
                else            vg[row * CDIM + col] = acc2[kt][ct][i];
            }

    // ---- asum: reduce over l15 lanes, lane0-of-16 writes ------------------
    #pragma unroll
    for (int kt = 0; kt < 2; ++kt)
        #pragma unroll
        for (int i = 0; i < 4; ++i) {
            float v = asr[kt][i];
            v += __shfl_xor(v, 1); v += __shfl_xor(v, 2);
            v += __shfl_xor(v, 4); v += __shfl_xor(v, 8);
            if (l15 == 0) {
                const int row = (2 * w + kt) * 16 + l4 * 4 + i;
                if (use_atomic) atomicAdd(&asout[n * KCL + row], v);
                else            asout[blockIdx.x * KCL + row] = v;
            }
        }
}

// ---------------------------------------------------------------------------
// Kernel 2: sum partials; vlad = V - asum*cent; intra-norm; global norm.
// NPARTS templated so the partial loop fully unrolls (independent loads).
// ---------------------------------------------------------------------------
template <int NPARTS>
__global__ __launch_bounds__(256)
void netvlad_finalize(const float* __restrict__ vpart,   // [N][NPARTS][K][C]
                      const float* __restrict__ aspart,  // [N][NPARTS][K]
                      const float* __restrict__ cent,    // [K][C]
                      float* __restrict__ out)           // [N][K*C]
{
    const int t = threadIdx.x;
    const int n  = blockIdx.x >> 3;
    const int kg = blockIdx.x & 7;
    const int k  = kg * 16 + (t >> 4);
    const int c0 = (t & 15) * 4;

    float vsum[4] = {0.f, 0.f, 0.f, 0.f};
    float av = 0.f;
    #pragma unroll
    for (int pt = 0; pt < NPARTS; ++pt) {
        const float* vg = vpart + (((size_t)n * NPARTS + pt) * KCL + k) * CDIM + c0;
        float4 a = *(const float4*)vg;
        vsum[0] += a.x; vsum[1] += a.y; vsum[2] += a.z; vsum[3] += a.w;
        av += aspart[(n * NPARTS + pt) * KCL + k];
    }

    float4 cq = *(const float4*)(cent + k * CDIM + c0);
    float cc[4] = {cq.x, cq.y, cq.z, cq.w};
    float ss = 0.f;
    #pragma unroll
    for (int j = 0; j < 4; ++j) {
        vsum[j] -= av * cc[j];
        ss += vsum[j] * vsum[j];
    }
    // row sumsq over the 16 lanes covering this k
    ss += __shfl_xor(ss, 1); ss += __shfl_xor(ss, 2);
    ss += __shfl_xor(ss, 4); ss += __shfl_xor(ss, 8);
    const float s = (1.0f / fmaxf(sqrtf(ss), 1e-12f)) * RSQRT128;

    float4 o;
    o.x = vsum[0] * s; o.y = vsum[1] * s; o.z = vsum[2] * s; o.w = vsum[3] * s;
    *(float4*)(out + (size_t)n * KCL * CDIM + k * CDIM + c0) = o;
}

// ---------------------------------------------------------------------------
extern "C" void kernel_launch(void* const* d_in, const int* in_sizes, int n_in,
                              void* d_out, int out_size, void* d_ws, size_t ws_size,
                              hipStream_t stream) {
    const float* x     = (const float*)d_in[0];   // [64,64,64,64]
    const float* cent  = (const float*)d_in[1];   // [128,64]
    const float* convw = (const float*)d_in[2];   // [128,64]
    const float* convb = (const float*)d_in[3];   // [128]
    float* out = (float*)d_out;

    const size_t need8 = (size_t)NIMG * 8 * (KCL * CDIM + KCL) * sizeof(float);

    if (ws_size >= need8) {
        float* vws  = (float*)d_ws;                               // [N][8][K][C]
        float* asws = vws + (size_t)NIMG * 8 * KCL * CDIM;        // [N][8][K]
        netvlad_main<8><<<dim3(NIMG * 8), dim3(256), 0, stream>>>(
            x, convw, convb, vws, asws, 0);
        netvlad_finalize<8><<<dim3(NIMG * 8), dim3(256), 0, stream>>>(
            vws, asws, cent, out);
    } else {
        float* vws  = (float*)d_ws;                               // [N][K][C]
        float* asws = vws + (size_t)NIMG * KCL * CDIM;            // [N][K]
        const size_t zb = (size_t)NIMG * (KCL * CDIM + KCL) * sizeof(float);
        hipMemsetAsync(d_ws, 0, zb, stream);
        netvlad_main<8><<<dim3(NIMG * 8), dim3(256), 0, stream>>>(
            x, convw, convb, vws, asws, 1);
        netvlad_finalize<1><<<dim3(NIMG * 8), dim3(256), 0, stream>>>(
            vws, asws, cent, out);
    }
}